// Round 3
// baseline (113.257 us; speedup 1.0000x reference)
//
#include <hip/hip_runtime.h>
#include <hip/hip_bf16.h>

#define NB 4
#define NC 32
#define NH 32
#define NW 32
#define KK 288                   // 32*3*3 patch length
#define PLANE (NB*NC*NH*NW)      // 131072 elements per (y,l,u) plane

// Norm-dist conv with fused weight zero-meaning.
// Block = 32(w) x 8(co). Grid = (h=32, cog=4, b=4).
// STAGE1: reads x/l/u planes, writes fp32 mid planes (relu no-op: all >= 0).
// STAGE2: reads mid planes, adds residual (x/l/u), relu, writes d_out.
template<bool STAGE2>
__global__ __launch_bounds__(256) void normdist_conv_k(
    const float* __restrict__ xb,     // residual planes (also stage-1 input)
    const float* __restrict__ lb,
    const float* __restrict__ ub,
    const float* __restrict__ my,     // stage-2 input planes (mid)
    const float* __restrict__ ml,
    const float* __restrict__ mu,
    const float* __restrict__ wraw,   // raw conv weights [32][288]
    float* __restrict__ oy, float* __restrict__ ol, float* __restrict__ ou,
    float* __restrict__ out)
{
    const int h   = blockIdx.x;
    const int cog = blockIdx.y;
    const int b   = blockIdx.z;
    const int tx  = threadIdx.x;      // w
    const int ty  = threadIdx.y;      // co within group of 8
    const int tid = ty * 32 + tx;

    // Patch halo, xlu-interleaved: [c][r][col][4] floats; col 0 == gw=-1 pad.
    __shared__ float4 sP[NC*3*34];         // 52224 B
    // Weights, padded: [co][c][r][4] floats (component 3 unused).
    __shared__ float  sWf[8*NC*3*4];       // 12288 B
    float4* sW4 = (float4*)sWf;

    // ---- stage raw weights for this co-group ----
    for (int i = tid; i < 8*KK; i += 256) {
        const int co  = i / KK;
        const int rem = i - co*KK;
        const int c   = rem / 9;
        const int r9  = rem - c*9;
        const int r   = r9 / 3;
        const int kw  = r9 - r*3;
        sWf[((co*NC + c)*3 + r)*4 + kw] = wraw[(cog*8 + co)*KK + rem];
    }

    // ---- stage patch halo ----
    for (int i = tid; i < NC*3*34; i += 256) {
        const int c   = i / 102;
        const int rem = i - c*102;
        const int r   = rem / 34;
        const int col = rem - r*34;
        const int gh  = h + r - 1;
        const int gw  = col - 1;
        float vx = 0.0f, vl = 0.0f, vu = 0.0f;
        if ((unsigned)gh < NH && (unsigned)gw < NW) {
            const int g = ((b*NC + c)*NH + gh)*NW + gw;
            if (STAGE2) { vx = my[g]; vl = ml[g]; vu = mu[g]; }
            else        { vx = xb[g]; vl = lb[g]; vu = ub[g]; }
        }
        sP[i] = make_float4(vx, vl, vu, 0.0f);
    }
    __syncthreads();

    // ---- zero-mean the 8 weight rows: thread (co=tid/32, c=tid&31) ----
    {
        const int co = tid >> 5;
        const int c  = tid & 31;
        float4 a0 = sW4[(co*NC + c)*3 + 0];
        float4 a1 = sW4[(co*NC + c)*3 + 1];
        float4 a2 = sW4[(co*NC + c)*3 + 2];
        float s = a0.x+a0.y+a0.z + a1.x+a1.y+a1.z + a2.x+a2.y+a2.z;
        #pragma unroll
        for (int off = 16; off > 0; off >>= 1) s += __shfl_xor(s, off, 32);
        const float mean = s * (1.0f / (float)KK);
        a0.x -= mean; a0.y -= mean; a0.z -= mean; a0.w = 0.0f;
        a1.x -= mean; a1.y -= mean; a1.z -= mean; a1.w = 0.0f;
        a2.x -= mean; a2.y -= mean; a2.z -= mean; a2.w = 0.0f;
        sW4[(co*NC + c)*3 + 0] = a0;
        sW4[(co*NC + c)*3 + 1] = a1;
        sW4[(co*NC + c)*3 + 2] = a2;
    }
    __syncthreads();

    float accY = 0.0f, accL = 0.0f, accU = 0.0f;

    auto tap = [&](float wv, float4 p) {
        // y: |px-wv|^8 = ((d^2)^2)^2, abs-free
        const float d  = p.x - wv;
        const float d2 = d*d, d4 = d2*d2;
        accY = fmaf(d4, d4, accY);
        // dl: max(pl-wv, wv-pu, 0)^8
        const float a  = p.y - wv;
        const float nb = wv - p.z;
        const float m  = fmaxf(fmaxf(a, nb), 0.0f);
        const float m2 = m*m, m4 = m2*m2;
        accL = fmaf(m4, m4, accL);
        // du: max(|pl-wv|,|pu-wv|)^8 = max(a^2,nb^2)^4
        const float a2 = a*a, q2 = nb*nb;
        const float mm2 = fmaxf(a2, q2);
        const float mm4 = mm2*mm2;
        accU = fmaf(mm4, mm4, accU);
    };

    #pragma unroll 4
    for (int c = 0; c < NC; ++c) {
        const float4 w0 = sW4[(ty*NC + c)*3 + 0];
        const float4 w1 = sW4[(ty*NC + c)*3 + 1];
        const float4 w2 = sW4[(ty*NC + c)*3 + 2];
        const int pb = c*3*34 + tx;
        const float4 p00 = sP[pb +   0], p01 = sP[pb +   1], p02 = sP[pb +   2];
        const float4 p10 = sP[pb +  34], p11 = sP[pb +  35], p12 = sP[pb +  36];
        const float4 p20 = sP[pb +  68], p21 = sP[pb +  69], p22 = sP[pb +  70];
        tap(w0.x, p00); tap(w0.y, p01); tap(w0.z, p02);
        tap(w1.x, p10); tap(w1.y, p11); tap(w1.z, p12);
        tap(w2.x, p20); tap(w2.y, p21); tap(w2.z, p22);
    }

    // x^(1/8) = sqrt(sqrt(sqrt(x))); all accs >= 0.
    const float y  = sqrtf(sqrtf(sqrtf(accY)));
    const float dl = sqrtf(sqrtf(sqrtf(accL)));
    const float du = sqrtf(sqrtf(sqrtf(accU)));

    const int co = cog*8 + ty;
    const int o  = ((b*NC + co)*NH + h)*NW + tx;
    if (!STAGE2) {
        oy[o] = y; ol[o] = dl; ou[o] = du;   // relu no-op: all >= 0
    } else {
        out[o]           = fmaxf(y  + xb[o], 0.0f);
        out[PLANE + o]   = fmaxf(dl + lb[o], 0.0f);
        out[2*PLANE + o] = fmaxf(du + ub[o], 0.0f);
    }
}

extern "C" void kernel_launch(void* const* d_in, const int* in_sizes, int n_in,
                              void* d_out, int out_size, void* d_ws, size_t ws_size,
                              hipStream_t stream)
{
    const float* x  = (const float*)d_in[0];
    const float* l  = (const float*)d_in[1];
    const float* u  = (const float*)d_in[2];
    const float* w1 = (const float*)d_in[3];
    const float* w2 = (const float*)d_in[4];
    float* ws = (float*)d_ws;
    float* my = ws;                       // 131072 floats each
    float* ml = my + PLANE;
    float* mu = ml + PLANE;
    float* out = (float*)d_out;

    dim3 blk(32, 8);
    dim3 grd(NH, 4, NB);
    normdist_conv_k<false><<<grd, blk, 0, stream>>>(x, l, u, nullptr, nullptr, nullptr,
                                                    w1, my, ml, mu, nullptr);
    normdist_conv_k<true ><<<grd, blk, 0, stream>>>(x, l, u, my, ml, mu,
                                                    w2, nullptr, nullptr, nullptr, out);
}

// Round 4
// 107.577 us; speedup vs baseline: 1.0528x; 1.0528x over previous
//
#include <hip/hip_runtime.h>

#define NB 4
#define NC 32
#define NH 32
#define NW 32
#define KK 288                   // 32*3*3 patch length
#define PLANE (NB*NC*NH*NW)      // 131072 elements per plane
#define CHALF 16                 // channels per block (split reduction)

__device__ __forceinline__ float s3(float v) { return sqrtf(sqrtf(sqrtf(v))); }

// Zero-mean weight rows; write padded float4 layout [co][c][r] = {w(r,0),w(r,1),w(r,2),pad}.
__global__ __launch_bounds__(256) void prep_weights_k(
        const float* __restrict__ w1, const float* __restrict__ w2,
        float* __restrict__ wf1, float* __restrict__ wf2)
{
    const int row = blockIdx.x;                   // 0..63
    const float* src = (row < NC) ? w1 : w2;
    float* dst = (row < NC) ? wf1 : wf2;
    const int co = row & (NC - 1);
    const int tid = threadIdx.x;
    __shared__ float red[256];
    const float a = src[co*KK + tid];                              // tid < 256 < 288
    const float b = (tid + 256 < KK) ? src[co*KK + tid + 256] : 0.0f;
    red[tid] = a + b;
    __syncthreads();
    for (int s = 128; s > 0; s >>= 1) {
        if (tid < s) red[tid] += red[tid + s];
        __syncthreads();
    }
    const float mean = red[0] * (1.0f / (float)KK);
    // element e -> float offset co*384 + (c*3+r)*4 + kw, where e = c*9 + r*3 + kw
    {
        const int e = tid, c = e / 9, r9 = e - c*9, r = r9 / 3, kw = r9 - r*3;
        dst[co*384 + ((c*3 + r) << 2) + kw] = a - mean;
    }
    if (tid + 256 < KK) {
        const int e = tid + 256, c = e / 9, r9 = e - c*9, r = r9 / 3, kw = r9 - r*3;
        dst[co*384 + ((c*3 + r) << 2) + kw] = b - mean;
    }
}

// Half-channel norm-dist conv. Block = 32(w) x 8(co). Grid = (h=32, cog*2+chalf=8, b=4).
// STAGE1: stages x/l/u directly. STAGE2: stages (p0+p1)^(1/8) from conv1 partials.
// Both write partial (pre-root) sums to pY/pL/pU at [chalf*PLANE + o].
template<bool STAGE2>
__global__ __launch_bounds__(256, 4) void normdist_conv_k(
    const float* __restrict__ sy,     // stage1: x plane | stage2: conv1 Y partials [2][PLANE]
    const float* __restrict__ sl,
    const float* __restrict__ su,
    const float* __restrict__ wf,     // prepped weights, float4 [co][c][r]
    float* __restrict__ pY, float* __restrict__ pL, float* __restrict__ pU)
{
    const int h     = blockIdx.x;
    const int cog   = blockIdx.y >> 1;
    const int chalf = blockIdx.y & 1;
    const int ch0   = chalf * CHALF;
    const int b     = blockIdx.z;
    const int tx    = threadIdx.x;
    const int ty    = threadIdx.y;
    const int tid   = ty * 32 + tx;

    // Patch halo, xlu-interleaved: [c<16][r<3][col<34] float4 (w unused). 26112 B.
    __shared__ float4 sP[CHALF*3*34];

    for (int i = tid; i < CHALF*3*34; i += 256) {
        const int c   = i / 102;
        const int rem = i - c*102;
        const int r   = rem / 34;
        const int col = rem - r*34;
        const int gh  = h + r - 1;
        const int gw  = col - 1;
        float vx = 0.0f, vl = 0.0f, vu = 0.0f;
        if ((unsigned)gh < NH && (unsigned)gw < NW) {
            const int g = ((b*NC + ch0 + c)*NH + gh)*NW + gw;
            if (STAGE2) {   // combine conv1 halves + eighth-root (relu no-op: >=0)
                vx = s3(sy[g] + sy[PLANE + g]);
                vl = s3(sl[g] + sl[PLANE + g]);
                vu = s3(su[g] + su[PLANE + g]);
            } else {
                vx = sy[g]; vl = sl[g]; vu = su[g];
            }
        }
        sP[i] = make_float4(vx, vl, vu, 0.0f);
    }
    __syncthreads();

    const int co = cog*8 + ty;
    const float4* wbase = (const float4*)wf + (co*NC + ch0)*3;

    float accY = 0.0f, accL = 0.0f, accU = 0.0f;

    auto tap = [&](float wv, float4 p) {
        const float d  = p.x - wv;          // y: |d|^8 = ((d^2)^2)^2
        const float d2 = d*d, d4 = d2*d2;
        accY = fmaf(d4, d4, accY);
        const float a  = p.y - wv;          // dl: max(a, nb, 0)^8
        const float nb = wv - p.z;
        const float m  = fmaxf(fmaxf(a, nb), 0.0f);
        const float m2 = m*m, m4 = m2*m2;
        accL = fmaf(m4, m4, accL);
        const float a2 = a*a, q2 = nb*nb;   // du: max(a^2, nb^2)^4
        const float mm2 = fmaxf(a2, q2);
        const float mm4 = mm2*mm2;
        accU = fmaf(mm4, mm4, accU);
    };

    #pragma unroll 2
    for (int c = 0; c < CHALF; ++c) {
        const float4 w0 = wbase[c*3 + 0];
        const float4 w1 = wbase[c*3 + 1];
        const float4 w2 = wbase[c*3 + 2];
        const int pb = c*102 + tx;
        tap(w0.x, sP[pb +  0]); tap(w0.y, sP[pb +  1]); tap(w0.z, sP[pb +  2]);
        tap(w1.x, sP[pb + 34]); tap(w1.y, sP[pb + 35]); tap(w1.z, sP[pb + 36]);
        tap(w2.x, sP[pb + 68]); tap(w2.y, sP[pb + 69]); tap(w2.z, sP[pb + 70]);
    }

    const int o = ((b*NC + co)*NH + h)*NW + tx;
    pY[chalf*PLANE + o] = accY;
    pL[chalf*PLANE + o] = accL;
    pU[chalf*PLANE + o] = accU;
}

// Combine conv2 halves, eighth-root, add residual, relu, write out.
__global__ __launch_bounds__(256) void epilogue_k(
    const float* __restrict__ pY, const float* __restrict__ pL, const float* __restrict__ pU,
    const float* __restrict__ x,  const float* __restrict__ l,  const float* __restrict__ u,
    float* __restrict__ out)
{
    const int o = blockIdx.x*256 + threadIdx.x;
    const float y  = s3(pY[o] + pY[PLANE + o]);
    const float dl = s3(pL[o] + pL[PLANE + o]);
    const float du = s3(pU[o] + pU[PLANE + o]);
    out[o]           = fmaxf(y  + x[o], 0.0f);
    out[PLANE + o]   = fmaxf(dl + l[o], 0.0f);
    out[2*PLANE + o] = fmaxf(du + u[o], 0.0f);
}

extern "C" void kernel_launch(void* const* d_in, const int* in_sizes, int n_in,
                              void* d_out, int out_size, void* d_ws, size_t ws_size,
                              hipStream_t stream)
{
    const float* x  = (const float*)d_in[0];
    const float* l  = (const float*)d_in[1];
    const float* u  = (const float*)d_in[2];
    const float* w1 = (const float*)d_in[3];
    const float* w2 = (const float*)d_in[4];
    float* ws  = (float*)d_ws;
    float* wf1 = ws;                        // 12288 floats (padded float4 layout)
    float* wf2 = wf1 + 12288;
    float* p1Y = wf2 + 12288;               // conv1 partials: [2][PLANE] each
    float* p1L = p1Y + 2*PLANE;
    float* p1U = p1L + 2*PLANE;
    float* p2Y = p1U + 2*PLANE;             // conv2 partials
    float* p2L = p2Y + 2*PLANE;
    float* p2U = p2L + 2*PLANE;
    float* out = (float*)d_out;

    prep_weights_k<<<64, 256, 0, stream>>>(w1, w2, wf1, wf2);

    dim3 blk(32, 8);
    dim3 grd(NH, 8, NB);                    // h, cog*2+chalf, b  -> 1024 blocks
    normdist_conv_k<false><<<grd, blk, 0, stream>>>(x, l, u, wf1, p1Y, p1L, p1U);
    normdist_conv_k<true ><<<grd, blk, 0, stream>>>(p1Y, p1L, p1U, wf2, p2Y, p2L, p2U);
    epilogue_k<<<PLANE/256, 256, 0, stream>>>(p2Y, p2L, p2U, x, l, u, out);
}